// Round 8
// baseline (1437.659 us; speedup 1.0000x reference)
//
#include <hip/hip_runtime.h>
#include <hip/hip_bf16.h>
#include <math.h>

#define BB 32
#define CC 64
#define C2 32
#define HH 32
#define WW 32
#define HW 1024
#define NTOT 3278
#define NPAD2 3328   // padded N (multiple of 128) for MFMA corr + fold
#define NT26 26      // NPAD2 / 128
#define KC 288       // correlation K = C2*9

typedef __bf16 bf16x8 __attribute__((ext_vector_type(8)));
typedef float  f32x4  __attribute__((ext_vector_type(4)));

__device__ __constant__ int SC_SIZE[5] = {32, 28, 25, 22, 19};
__device__ __constant__ int SC_OFF[6]  = {0, 1024, 1808, 2433, 2917, 3278};

// ---------------- fused feature kernel: LDS-staged, x read once ----------------
#define XS_STR 65
#define WS_STR 132
__global__ void __launch_bounds__(256, 1) k_feats(
        const float* __restrict__ x,
        const float* __restrict__ wb, const float* __restrict__ bb, const float* __restrict__ ab,
        const float* __restrict__ wm, const float* __restrict__ bm, const float* __restrict__ am,
        const float* __restrict__ wa, const float* __restrict__ ba, const float* __restrict__ aa,
        float* __restrict__ mb, float* __restrict__ rmf, __bf16* __restrict__ basef,
        float* __restrict__ mbss, float* __restrict__ rmss) {
    __shared__ float Xs[64 * XS_STR];     // [c][p]
    __shared__ float Wls[64 * WS_STR];    // [c][o]
    __shared__ float bsh[128];
    __shared__ float ash3[3];
    int tid = threadIdx.x;
    int g0 = blockIdx.x * 64;
    int b = g0 >> 10, p0 = g0 & 1023;

    const float* xb = x + (size_t)b * CC * HW + p0;
    for (int i = tid; i < 64 * 64; i += 256) {
        int c = i >> 6, p = i & 63;
        Xs[c * XS_STR + p] = xb[(size_t)c * HW + p];
    }
    for (int i = tid; i < 128 * 64; i += 256) {
        int o = i >> 6, c = i & 63;
        float w = (o < 32) ? wb[o * CC + c] : (o < 64) ? wm[(o - 32) * CC + c] : wa[(o - 64) * CC + c];
        Wls[c * WS_STR + o] = w;
    }
    if (tid < 128) bsh[tid] = (tid < 32) ? bb[tid] : (tid < 64) ? bm[tid - 32] : ba[tid - 64];
    if (tid == 128) ash3[0] = ab[0];
    if (tid == 129) ash3[1] = am[0];
    if (tid == 130) ash3[2] = aa[0];
    __syncthreads();

    int p = tid & 63, og = tid >> 6;
    int o0 = og * 32;
    float acc[32];
#pragma unroll
    for (int oi = 0; oi < 32; ++oi) acc[oi] = bsh[o0 + oi];
    for (int c = 0; c < 64; ++c) {
        float xv = Xs[c * XS_STR + p];
        const float* wr = &Wls[c * WS_STR + o0];
#pragma unroll
        for (int oi = 0; oi < 32; ++oi) acc[oi] += wr[oi] * xv;
    }
    int pp = p0 + p;
    if (og == 0) {
        float alpha = ash3[0], ss = 0.f;
#pragma unroll
        for (int oi = 0; oi < 32; ++oi) {
            float v = acc[oi] >= 0.f ? acc[oi] : alpha * acc[oi];
            mb[((size_t)b * C2 + oi) * HW + pp] = v;
            ss += v * v;
        }
        mbss[(size_t)b * HW + pp] = ss;
    } else if (og == 1) {
        float alpha = ash3[1], ss = 0.f;
#pragma unroll
        for (int oi = 0; oi < 32; ++oi) {
            float v = acc[oi] >= 0.f ? acc[oi] : alpha * acc[oi];
            rmf[((size_t)b * C2 + oi) * HW + pp] = v;
            ss += v * v;
        }
        rmss[(size_t)b * HW + pp] = ss;
    } else {
        float alpha = ash3[2];
        int ob = o0 - 64;
#pragma unroll
        for (int oi = 0; oi < 32; ++oi) {
            float v = acc[oi] >= 0.f ? acc[oi] : alpha * acc[oi];
            basef[((size_t)b * CC + ob + oi) * HW + pp] = (__bf16)v;
        }
    }
}

// ---------------- neighbor table ----------------
__global__ void k_nbr(int* __restrict__ nbr_pos) {
    int n = blockIdx.x * blockDim.x + threadIdx.x;
    if (n >= NTOT) return;
    int s = 0;
    while (s < 4 && n >= SC_OFF[s + 1]) ++s;
    int q = n - SC_OFF[s];
    int hs = SC_SIZE[s];
    int ny = q / hs, nx = q % hs;
    for (int dy = 0; dy < 3; ++dy)
        for (int dx = 0; dx < 3; ++dx) {
            int yy = ny + dy - 1, xx = nx + dx - 1;
            int pos = -1;
            if (yy >= 0 && yy < hs && xx >= 0 && xx < hs)
                pos = ((yy * HH) / hs) * WW + (xx * WW) / hs;
            nbr_pos[(dy * 3 + dx) * NTOT + n] = pos;
        }
}

// ---------------- per-(b,p) logit upper bound ----------------
__global__ void k_qnorm(const float* __restrict__ mbss, float* __restrict__ qub) {
    int t = blockIdx.x * blockDim.x + threadIdx.x;
    int b = t >> 10, p = t & 1023;
    int y = p >> 5, x = p & 31;
    float s = 0.f;
#pragma unroll
    for (int dy = 0; dy < 3; ++dy)
#pragma unroll
        for (int dx = 0; dx < 3; ++dx) {
            int yy = y + dy - 1, xx = x + dx - 1;
            if (yy >= 0 && yy < HH && xx >= 0 && xx < WW)
                s += mbss[(size_t)b * HW + yy * WW + xx];
        }
    qub[t] = 10.0f * sqrtf(s);
}

// ---------------- per-(b,n) filter norms ----------------
__global__ void k_norms(const float* __restrict__ rmss, const int* __restrict__ nbr_pos,
                        float* __restrict__ sinv) {
    int t = blockIdx.x * blockDim.x + threadIdx.x;
    if (t >= BB * NTOT) return;
    int b = t / NTOT, n = t % NTOT;
    float sum = 0.f;
#pragma unroll
    for (int kk = 0; kk < 9; ++kk) {
        int pos = nbr_pos[kk * NTOT + n];
        if (pos >= 0) sum += rmss[(size_t)b * HW + pos];
    }
    sinv[t] = 10.0f / fmaxf(sqrtf(sum), 1e-4f);
}

// ---------------- correlation GEMM: fused gather staging + split-bf16 MFMA + exp epilogue ----------------
__global__ void k_corr_mfma(const float* __restrict__ mb, const float* __restrict__ rmf,
                            const int* __restrict__ nbr_pos,
                            const float* __restrict__ sinv, const float* __restrict__ qub,
                            __bf16* __restrict__ tbuf, float* __restrict__ partS, int b0) {
    int ptile = blockIdx.x;   // 16 tiles of 64 p
    int ntile = blockIdx.y;   // 26 tiles of 128 n
    int cb    = blockIdx.z;
    int tid  = threadIdx.x;
    int lane = tid & 63, wave = tid >> 6;
    int row16 = lane & 15, quad = lane >> 4;
    int p0 = ptile * 64, n0 = ntile * 128;

    __shared__ __bf16 Ah[64 * 40], Al[64 * 40];
    __shared__ __bf16 Bh[128 * 40], Bl[128 * 40];
    __shared__ int   nbrs[9][128];
    __shared__ float sMub[64];
    __shared__ float redS[4][64];

    if (tid < 64) sMub[tid] = qub[(size_t)(b0 + cb) * HW + p0 + tid];
    for (int i = tid; i < 9 * 128; i += 256) {
        int kk = i >> 7, j = i & 127;
        int n = n0 + j;
        nbrs[kk][j] = (n < NTOT) ? nbr_pos[kk * NTOT + n] : -1;
    }

    const float* mbb = mb  + (size_t)(b0 + cb) * C2 * HW;
    const float* rmb = rmf + (size_t)(b0 + cb) * C2 * HW;

    f32x4 acc[4][2];
#pragma unroll
    for (int i = 0; i < 4; ++i)
#pragma unroll
        for (int j = 0; j < 2; ++j) acc[i][j] = (f32x4){0.f, 0.f, 0.f, 0.f};

    __syncthreads();   // nbrs ready

    int ap = tid & 63, akq = tid >> 6;         // A task: (p, 8 k's)
    int ay = (p0 + ap) >> 5, ax = (p0 + ap) & 31;
    for (int k0 = 0; k0 < KC; k0 += 32) {
        // ---- A: gather mb patches, split hi/lo ----
        {
            bf16x8 hi8, lo8;
#pragma unroll
            for (int u = 0; u < 8; ++u) {
                int k = k0 + akq * 8 + u;
                int c2 = k / 9, kk = k - c2 * 9;
                int py = ay + kk / 3 - 1, px = ax + (kk % 3) - 1;
                float v = 0.f;
                if (py >= 0 && py < HH && px >= 0 && px < WW)
                    v = mbb[(size_t)c2 * HW + py * WW + px];
                __bf16 h = (__bf16)v;
                hi8[u] = h;
                lo8[u] = (__bf16)(v - (float)h);
            }
            *(bf16x8*)&Ah[ap * 40 + akq * 8] = hi8;
            *(bf16x8*)&Al[ap * 40 + akq * 8] = lo8;
        }
        // ---- B: gather wi rows via nbrs, split hi/lo ----
#pragma unroll
        for (int it = 0; it < 2; ++it) {
            int tt = tid + it * 256;
            int bj = tt & 127, bkq = (tt >> 7) & 3;
            bf16x8 hi8, lo8;
#pragma unroll
            for (int u = 0; u < 8; ++u) {
                int k = k0 + bkq * 8 + u;
                int c2 = k / 9, kk = k - c2 * 9;
                int pos = nbrs[kk][bj];
                float v = (pos >= 0) ? rmb[(size_t)c2 * HW + pos] : 0.f;
                __bf16 h = (__bf16)v;
                hi8[u] = h;
                lo8[u] = (__bf16)(v - (float)h);
            }
            *(bf16x8*)&Bh[bj * 40 + bkq * 8] = hi8;
            *(bf16x8*)&Bl[bj * 40 + bkq * 8] = lo8;
        }
        __syncthreads();
        bf16x8 ah[4], al[4], bh[2], bl[2];
#pragma unroll
        for (int m = 0; m < 4; ++m) {
            ah[m] = *(const bf16x8*)&Ah[(m * 16 + row16) * 40 + quad * 8];
            al[m] = *(const bf16x8*)&Al[(m * 16 + row16) * 40 + quad * 8];
        }
#pragma unroll
        for (int nb = 0; nb < 2; ++nb) {
            bh[nb] = *(const bf16x8*)&Bh[(wave * 32 + nb * 16 + row16) * 40 + quad * 8];
            bl[nb] = *(const bf16x8*)&Bl[(wave * 32 + nb * 16 + row16) * 40 + quad * 8];
        }
#pragma unroll
        for (int m = 0; m < 4; ++m)
#pragma unroll
            for (int nb = 0; nb < 2; ++nb) {
                acc[m][nb] = __builtin_amdgcn_mfma_f32_16x16x32_bf16(ah[m], bh[nb], acc[m][nb], 0, 0, 0);
                acc[m][nb] = __builtin_amdgcn_mfma_f32_16x16x32_bf16(ah[m], bl[nb], acc[m][nb], 0, 0, 0);
                acc[m][nb] = __builtin_amdgcn_mfma_f32_16x16x32_bf16(al[m], bh[nb], acc[m][nb], 0, 0, 0);
            }
        __syncthreads();
    }

    // ---- epilogue: v = acc*sinv[n]; t = exp(v - Mub[p]); row-partial sums ----
    int nn[2];
    float sv[2];
    bool valid[2];
#pragma unroll
    for (int nb = 0; nb < 2; ++nb) {
        nn[nb] = n0 + wave * 32 + nb * 16 + row16;
        valid[nb] = nn[nb] < NTOT;
        sv[nb] = valid[nb] ? sinv[(size_t)(b0 + cb) * NTOT + nn[nb]] : 0.f;
    }
    float sm[4][4] = {};
#pragma unroll
    for (int m = 0; m < 4; ++m)
#pragma unroll
        for (int nb = 0; nb < 2; ++nb) {
            size_t rb = ((size_t)cb * HW + p0 + m * 16) * NPAD2 + nn[nb];
#pragma unroll
            for (int r = 0; r < 4; ++r) {
                float mub = sMub[m * 16 + quad * 4 + r];
                float e = valid[nb] ? __expf(acc[m][nb][r] * sv[nb] - mub) : 0.f;
                tbuf[rb + (size_t)(quad * 4 + r) * NPAD2] = (__bf16)e;
                sm[m][r] += e;
            }
        }
#pragma unroll
    for (int msk = 1; msk < 16; msk <<= 1)
#pragma unroll
        for (int m = 0; m < 4; ++m)
#pragma unroll
            for (int r = 0; r < 4; ++r) sm[m][r] += __shfl_xor(sm[m][r], msk, 64);
    if (row16 == 0)
#pragma unroll
        for (int m = 0; m < 4; ++m)
#pragma unroll
            for (int r = 0; r < 4; ++r) redS[wave][m * 16 + quad * 4 + r] = sm[m][r];
    __syncthreads();
    if (wave == 0 && row16 == 0) {
#pragma unroll
        for (int m = 0; m < 4; ++m)
#pragma unroll
            for (int r = 0; r < 4; ++r) {
                int p = m * 16 + quad * 4 + r;
                float S = redS[0][p] + redS[1][p] + redS[2][p] + redS[3][p];
                partS[((size_t)cb * HW + p0 + p) * NT26 + ntile] = S;
            }
    }
}

// ---------------- row sum reduce ----------------
__global__ void k_rowsum(const float* __restrict__ partS, float* __restrict__ fin) {
    int row = blockIdx.x * 256 + threadIdx.x;
    float s = 0.f;
#pragma unroll
    for (int nt = 0; nt < NT26; ++nt) s += partS[(size_t)row * NT26 + nt];
    fin[row] = 1.0f / fmaxf(s, 1e-38f);
}

// ---------------- fold GEMM (MFMA bf16, fused V gather) ----------------
#define FSTR 72
__global__ void k_fold_mfma(const __bf16* __restrict__ basef, const int* __restrict__ nbr_pos,
                            const __bf16* __restrict__ tbuf, const float* __restrict__ fin,
                            float* __restrict__ outacc, int b0) {
    int ptile = blockIdx.x;   // 8 tiles of 128 p
    int mtile = blockIdx.y;   // 9 tiles of 64 m
    int cb    = blockIdx.z;
    int tid  = threadIdx.x;
    int lane = tid & 63, wave = tid >> 6;
    int row16 = lane & 15, quad = lane >> 4;
    int m0 = mtile * 64;

    __shared__ __bf16 Als[64 * FSTR];
    __shared__ __bf16 Bls[128 * FSTR];

    const __bf16* bfp = basef + (size_t)(b0 + cb) * CC * HW;
    const __bf16* Pp  = tbuf + (size_t)cb * HW * NPAD2 + (size_t)ptile * 128 * NPAD2;

    f32x4 acc[4][2];
#pragma unroll
    for (int i = 0; i < 4; ++i)
#pragma unroll
        for (int j = 0; j < 2; ++j) acc[i][j] = (f32x4){0.f, 0.f, 0.f, 0.f};

    int sr = tid >> 3, sk = (tid & 7) * 8;   // B staging coords
    for (int k0 = 0; k0 < NPAD2; k0 += 64) {
        // ---- A: gather V[m][n] = basef[c][nbr_kk(n)] ----
#pragma unroll
        for (int it = 0; it < 2; ++it) {
            int tt = tid + it * 256;
            int mi = tt >> 3, nq = (tt & 7) * 8;
            int mg = m0 + mi;
            int c = mg / 9, kk = mg - c * 9;
            const int* nb = &nbr_pos[kk * NTOT];
            bf16x8 v8;
#pragma unroll
            for (int u = 0; u < 8; ++u) {
                int n = k0 + nq + u;
                __bf16 v = (__bf16)0.f;
                if (n < NTOT) {
                    int pos = nb[n];
                    if (pos >= 0) v = bfp[(size_t)c * HW + pos];
                }
                v8[u] = v;
            }
            *(bf16x8*)&Als[mi * FSTR + nq] = v8;
        }
        // ---- B: tbuf tile (vector loads) ----
#pragma unroll
        for (int i = 0; i < 4; ++i)
            *(bf16x8*)&Bls[(i * 32 + sr) * FSTR + sk] =
                *(const bf16x8*)(Pp + (size_t)(i * 32 + sr) * NPAD2 + k0 + sk);
        __syncthreads();
#pragma unroll
        for (int kh = 0; kh < 2; ++kh) {
            bf16x8 af[4], bf[2];
#pragma unroll
            for (int mb = 0; mb < 4; ++mb)
                af[mb] = *(const bf16x8*)&Als[(mb * 16 + row16) * FSTR + kh * 32 + quad * 8];
#pragma unroll
            for (int pbi = 0; pbi < 2; ++pbi)
                bf[pbi] = *(const bf16x8*)&Bls[(wave * 32 + pbi * 16 + row16) * FSTR + kh * 32 + quad * 8];
#pragma unroll
            for (int mb = 0; mb < 4; ++mb)
#pragma unroll
                for (int pbi = 0; pbi < 2; ++pbi)
                    acc[mb][pbi] = __builtin_amdgcn_mfma_f32_16x16x32_bf16(af[mb], bf[pbi], acc[mb][pbi], 0, 0, 0);
        }
        __syncthreads();
    }
    float fsc[2];
#pragma unroll
    for (int pbi = 0; pbi < 2; ++pbi)
        fsc[pbi] = fin[(size_t)cb * HW + ptile * 128 + wave * 32 + pbi * 16 + row16];
#pragma unroll
    for (int mb = 0; mb < 4; ++mb)
#pragma unroll
        for (int pbi = 0; pbi < 2; ++pbi) {
#pragma unroll
            for (int r = 0; r < 4; ++r) {
                int mg = m0 + mb * 16 + quad * 4 + r;
                int pg = ptile * 128 + wave * 32 + pbi * 16 + row16;
                outacc[((size_t)cb * 576 + mg) * HW + pg] = acc[mb][pbi][r] * fsc[pbi];
            }
        }
}

// ---------------- epilogue ----------------
__global__ void k_epilogue(const float* __restrict__ x, const float* __restrict__ outacc,
                           float* __restrict__ out, int b0) {
    int t = blockIdx.x * blockDim.x + threadIdx.x;
    int cb = t >> 16;
    int c = (t >> 10) & 63;
    int p = t & 1023;
    int b = b0 + cb;
    int y = p >> 5, xx = p & 31;
    float acc = 0.f;
#pragma unroll
    for (int ky = 0; ky < 3; ++ky)
#pragma unroll
        for (int kx = 0; kx < 3; ++kx) {
            int py = y + 1 - ky, px = xx + 1 - kx;
            if (py >= 0 && py < HH && px >= 0 && px < WW)
                acc += outacc[((size_t)cb * 576 + c * 9 + ky * 3 + kx) * HW + py * WW + px];
        }
    size_t o = ((size_t)b * CC + c) * HW + p;
    out[o] = x[o] + 0.25f * acc;
}

extern "C" void kernel_launch(void* const* d_in, const int* in_sizes, int n_in,
                              void* d_out, int out_size, void* d_ws, size_t ws_size,
                              hipStream_t stream) {
    const float* x       = (const float*)d_in[0];
    const float* w_base  = (const float*)d_in[1];
    const float* b_base  = (const float*)d_in[2];
    const float* a_base  = (const float*)d_in[3];
    const float* w_match = (const float*)d_in[4];
    const float* b_match = (const float*)d_in[5];
    const float* a_match = (const float*)d_in[6];
    const float* w_asm   = (const float*)d_in[7];
    const float* b_asm   = (const float*)d_in[8];
    const float* a_asm   = (const float*)d_in[9];
    float* out = (float*)d_out;

    const size_t fixed = ((size_t)BB * C2 * HW * 4) * 2 + ((size_t)BB * CC * HW * 2) +
                         ((size_t)BB * HW * 4) * 3 + ((size_t)BB * NTOT * 4) +
                         ((size_t)9 * NTOT * 4) + 65536;
    const size_t perCB = ((size_t)HW * NPAD2 * 2) + ((size_t)HW * NT26 * 4) +
                         ((size_t)HW * 4) + ((size_t)576 * HW * 4) + 65536;
    int CB = 32;
    while (CB > 1 && fixed + perCB * CB > ws_size) CB >>= 1;

    char* ws = (char*)d_ws;
    size_t off = 0;
    auto alloc_b = [&](size_t bytes) {
        void* p = (void*)(ws + off);
        off += bytes;
        off = (off + 255) & ~(size_t)255;
        return p;
    };
    float*  mb      = (float*)alloc_b((size_t)BB * C2 * HW * 4);
    float*  rm_full = (float*)alloc_b((size_t)BB * C2 * HW * 4);
    __bf16* base_f  = (__bf16*)alloc_b((size_t)BB * CC * HW * 2);
    float*  mbss    = (float*)alloc_b((size_t)BB * HW * 4);
    float*  rmss    = (float*)alloc_b((size_t)BB * HW * 4);
    float*  qub     = (float*)alloc_b((size_t)BB * HW * 4);
    float*  sinv    = (float*)alloc_b((size_t)BB * NTOT * 4);
    int*    nbr_pos = (int*)alloc_b((size_t)9 * NTOT * 4);
    __bf16* tbuf    = (__bf16*)alloc_b((size_t)CB * HW * NPAD2 * 2);
    float*  partS   = (float*)alloc_b((size_t)CB * HW * NT26 * 4);
    float*  fin     = (float*)alloc_b((size_t)CB * HW * 4);
    float*  outacc  = (float*)alloc_b((size_t)CB * 576 * HW * 4);
    if (off > ws_size) return;

    k_feats<<<BB * HW / 64, 256, 0, stream>>>(
        x, w_base, b_base, a_base, w_match, b_match, a_match, w_asm, b_asm, a_asm,
        mb, rm_full, base_f, mbss, rmss);
    k_nbr<<<(NTOT + 255) / 256, 256, 0, stream>>>(nbr_pos);
    k_qnorm<<<BB * HW / 256, 256, 0, stream>>>(mbss, qub);
    k_norms<<<(BB * NTOT + 255) / 256, 256, 0, stream>>>(rmss, nbr_pos, sinv);

    for (int b0 = 0; b0 < BB; b0 += CB) {
        k_corr_mfma<<<dim3(16, NT26, CB), 256, 0, stream>>>(
            mb, rm_full, nbr_pos, sinv, qub, tbuf, partS, b0);
        k_rowsum<<<CB * HW / 256, 256, 0, stream>>>(partS, fin);
        k_fold_mfma<<<dim3(8, 9, CB), 256, 0, stream>>>(base_f, nbr_pos, tbuf, fin, outacc, b0);
        k_epilogue<<<CB * CC * HW / 256, 256, 0, stream>>>(x, outacc, out, b0);
    }
}

// Round 9
// 942.254 us; speedup vs baseline: 1.5258x; 1.5258x over previous
//
#include <hip/hip_runtime.h>
#include <hip/hip_bf16.h>
#include <math.h>

#define BB 32
#define CC 64
#define C2 32
#define HH 32
#define WW 32
#define HW 1024
#define NTOT 3278
#define NPAD2 3328   // padded N (multiple of 128) for MFMA corr + fold
#define NT26 26      // NPAD2 / 128
#define KC 288       // correlation K = C2*9

typedef __bf16 bf16x8 __attribute__((ext_vector_type(8)));
typedef float  f32x4  __attribute__((ext_vector_type(4)));

__device__ __constant__ int SC_SIZE[5] = {32, 28, 25, 22, 19};
__device__ __constant__ int SC_OFF[6]  = {0, 1024, 1808, 2433, 2917, 3278};

// ---------------- fused feature kernel: LDS-staged, x read once ----------------
#define XS_STR 65
#define WS_STR 132
__global__ void __launch_bounds__(256, 1) k_feats(
        const float* __restrict__ x,
        const float* __restrict__ wb, const float* __restrict__ bb, const float* __restrict__ ab,
        const float* __restrict__ wm, const float* __restrict__ bm, const float* __restrict__ am,
        const float* __restrict__ wa, const float* __restrict__ ba, const float* __restrict__ aa,
        float* __restrict__ mb, float* __restrict__ rmf, __bf16* __restrict__ basef,
        float* __restrict__ mbss, float* __restrict__ rmss) {
    __shared__ float Xs[64 * XS_STR];     // [c][p]
    __shared__ float Wls[64 * WS_STR];    // [c][o]
    __shared__ float bsh[128];
    __shared__ float ash3[3];
    int tid = threadIdx.x;
    int g0 = blockIdx.x * 64;
    int b = g0 >> 10, p0 = g0 & 1023;

    const float* xb = x + (size_t)b * CC * HW + p0;
    for (int i = tid; i < 64 * 64; i += 256) {
        int c = i >> 6, p = i & 63;
        Xs[c * XS_STR + p] = xb[(size_t)c * HW + p];
    }
    for (int i = tid; i < 128 * 64; i += 256) {
        int o = i >> 6, c = i & 63;
        float w = (o < 32) ? wb[o * CC + c] : (o < 64) ? wm[(o - 32) * CC + c] : wa[(o - 64) * CC + c];
        Wls[c * WS_STR + o] = w;
    }
    if (tid < 128) bsh[tid] = (tid < 32) ? bb[tid] : (tid < 64) ? bm[tid - 32] : ba[tid - 64];
    if (tid == 128) ash3[0] = ab[0];
    if (tid == 129) ash3[1] = am[0];
    if (tid == 130) ash3[2] = aa[0];
    __syncthreads();

    int p = tid & 63, og = tid >> 6;
    int o0 = og * 32;
    float acc[32];
#pragma unroll
    for (int oi = 0; oi < 32; ++oi) acc[oi] = bsh[o0 + oi];
    for (int c = 0; c < 64; ++c) {
        float xv = Xs[c * XS_STR + p];
        const float* wr = &Wls[c * WS_STR + o0];
#pragma unroll
        for (int oi = 0; oi < 32; ++oi) acc[oi] += wr[oi] * xv;
    }
    int pp = p0 + p;
    if (og == 0) {
        float alpha = ash3[0], ss = 0.f;
#pragma unroll
        for (int oi = 0; oi < 32; ++oi) {
            float v = acc[oi] >= 0.f ? acc[oi] : alpha * acc[oi];
            mb[((size_t)b * C2 + oi) * HW + pp] = v;
            ss += v * v;
        }
        mbss[(size_t)b * HW + pp] = ss;
    } else if (og == 1) {
        float alpha = ash3[1], ss = 0.f;
#pragma unroll
        for (int oi = 0; oi < 32; ++oi) {
            float v = acc[oi] >= 0.f ? acc[oi] : alpha * acc[oi];
            rmf[((size_t)b * C2 + oi) * HW + pp] = v;
            ss += v * v;
        }
        rmss[(size_t)b * HW + pp] = ss;
    } else {
        float alpha = ash3[2];
        int ob = o0 - 64;
#pragma unroll
        for (int oi = 0; oi < 32; ++oi) {
            float v = acc[oi] >= 0.f ? acc[oi] : alpha * acc[oi];
            basef[((size_t)b * CC + ob + oi) * HW + pp] = (__bf16)v;
        }
    }
}

// ---------------- neighbor table ----------------
__global__ void k_nbr(int* __restrict__ nbr_pos) {
    int n = blockIdx.x * blockDim.x + threadIdx.x;
    if (n >= NTOT) return;
    int s = 0;
    while (s < 4 && n >= SC_OFF[s + 1]) ++s;
    int q = n - SC_OFF[s];
    int hs = SC_SIZE[s];
    int ny = q / hs, nx = q % hs;
    for (int dy = 0; dy < 3; ++dy)
        for (int dx = 0; dx < 3; ++dx) {
            int yy = ny + dy - 1, xx = nx + dx - 1;
            int pos = -1;
            if (yy >= 0 && yy < hs && xx >= 0 && xx < hs)
                pos = ((yy * HH) / hs) * WW + (xx * WW) / hs;
            nbr_pos[(dy * 3 + dx) * NTOT + n] = pos;
        }
}

// ---------------- per-(b,p) logit upper bound ----------------
__global__ void k_qnorm(const float* __restrict__ mbss, float* __restrict__ qub) {
    int t = blockIdx.x * blockDim.x + threadIdx.x;
    int b = t >> 10, p = t & 1023;
    int y = p >> 5, x = p & 31;
    float s = 0.f;
#pragma unroll
    for (int dy = 0; dy < 3; ++dy)
#pragma unroll
        for (int dx = 0; dx < 3; ++dx) {
            int yy = y + dy - 1, xx = x + dx - 1;
            if (yy >= 0 && yy < HH && xx >= 0 && xx < WW)
                s += mbss[(size_t)b * HW + yy * WW + xx];
        }
    qub[t] = 10.0f * sqrtf(s);
}

// ---------------- per-(b,n) filter norms ----------------
__global__ void k_norms(const float* __restrict__ rmss, const int* __restrict__ nbr_pos,
                        float* __restrict__ sinv) {
    int t = blockIdx.x * blockDim.x + threadIdx.x;
    if (t >= BB * NTOT) return;
    int b = t / NTOT, n = t % NTOT;
    float sum = 0.f;
#pragma unroll
    for (int kk = 0; kk < 9; ++kk) {
        int pos = nbr_pos[kk * NTOT + n];
        if (pos >= 0) sum += rmss[(size_t)b * HW + pos];
    }
    sinv[t] = 10.0f / fmaxf(sqrtf(sum), 1e-4f);
}

// ---------------- xpat gather (vectorized): thread -> 8 k's, one bf16x8 store each ----------------
__global__ void k_xpat(const float* __restrict__ mb, __bf16* __restrict__ xh,
                       __bf16* __restrict__ xl, int b0) {
    int t = blockIdx.x * 256 + threadIdx.x;   // over HW*36
    int cb = blockIdx.y;
    int p = t / 36, kq = t % 36;
    int py0 = p >> 5, px0 = p & 31;
    const float* mbb = mb + (size_t)(b0 + cb) * C2 * HW;
    bf16x8 hi8, lo8;
#pragma unroll
    for (int u = 0; u < 8; ++u) {
        int k = kq * 8 + u;
        int c2 = k / 9, kk = k - c2 * 9;
        int py = py0 + kk / 3 - 1, px = px0 + (kk % 3) - 1;
        float v = 0.f;
        if (py >= 0 && py < HH && px >= 0 && px < WW)
            v = mbb[(size_t)c2 * HW + py * WW + px];
        __bf16 h = (__bf16)v;
        hi8[u] = h;
        lo8[u] = (__bf16)(v - (float)h);
    }
    size_t o = ((size_t)cb * HW + p) * KC + kq * 8;
    *(bf16x8*)&xh[o] = hi8;
    *(bf16x8*)&xl[o] = lo8;
}

// ---------------- wib gather (vectorized) ----------------
__global__ void k_wib(const float* __restrict__ rmf, const int* __restrict__ nbr_pos,
                      __bf16* __restrict__ wh, __bf16* __restrict__ wl, int b0) {
    int t = blockIdx.x * 256 + threadIdx.x;   // over NPAD2*36
    int cb = blockIdx.y;
    int n = t / 36, kq = t % 36;
    const float* rmb = rmf + (size_t)(b0 + cb) * C2 * HW;
    bf16x8 hi8, lo8;
    if (n < NTOT) {
#pragma unroll
        for (int u = 0; u < 8; ++u) {
            int k = kq * 8 + u;
            int c2 = k / 9, kk = k - c2 * 9;
            int pos = nbr_pos[kk * NTOT + n];
            float v = (pos >= 0) ? rmb[(size_t)c2 * HW + pos] : 0.f;
            __bf16 h = (__bf16)v;
            hi8[u] = h;
            lo8[u] = (__bf16)(v - (float)h);
        }
    } else {
#pragma unroll
        for (int u = 0; u < 8; ++u) { hi8[u] = (__bf16)0.f; lo8[u] = (__bf16)0.f; }
    }
    size_t o = ((size_t)cb * NPAD2 + n) * KC + kq * 8;
    *(bf16x8*)&wh[o] = hi8;
    *(bf16x8*)&wl[o] = lo8;
}

// ---------------- V gather (vectorized): thread -> 8 consecutive n ----------------
__global__ void k_vgather(const __bf16* __restrict__ basef, const int* __restrict__ nbr_pos,
                          __bf16* __restrict__ Vb, int b0) {
    int t = blockIdx.x * 256 + threadIdx.x;   // over 576*(NPAD2/8)
    int cb = blockIdx.y;
    int m = t / (NPAD2 / 8), nq = t % (NPAD2 / 8);
    int c = m / 9, kk = m - c * 9;
    const __bf16* bfp = basef + ((size_t)(b0 + cb) * CC + c) * HW;
    const int* nb = &nbr_pos[kk * NTOT];
    int n0 = nq * 8;
    bf16x8 v8;
#pragma unroll
    for (int u = 0; u < 8; ++u) {
        int n = n0 + u;
        __bf16 v = (__bf16)0.f;
        if (n < NTOT) {
            int pos = nb[n];
            if (pos >= 0) v = bfp[pos];
        }
        v8[u] = v;
    }
    *(bf16x8*)&Vb[((size_t)cb * 576 + m) * NPAD2 + n0] = v8;
}

// ---------------- correlation GEMM (MFMA, split-bf16) + t = exp(v - Mub[p]) epilogue ----------------
__global__ void k_corr_mfma(const __bf16* __restrict__ xh, const __bf16* __restrict__ xl,
                            const __bf16* __restrict__ wh, const __bf16* __restrict__ wl,
                            const float* __restrict__ sinv, const float* __restrict__ qub,
                            __bf16* __restrict__ tbuf, float* __restrict__ partS, int b0) {
    int ptile = blockIdx.x;   // 16 tiles of 64 p
    int ntile = blockIdx.y;   // 26 tiles of 128 n
    int cb    = blockIdx.z;
    int tid  = threadIdx.x;
    int lane = tid & 63, wave = tid >> 6;
    int row16 = lane & 15, quad = lane >> 4;

    __shared__ __bf16 Ah[64 * 40], Al[64 * 40];
    __shared__ __bf16 Bh[128 * 40], Bl[128 * 40];
    __shared__ float sMub[64];
    __shared__ float redS[4][64];

    if (tid < 64) sMub[tid] = qub[(size_t)(b0 + cb) * HW + ptile * 64 + tid];

    const __bf16* Aph = xh + ((size_t)cb * HW + ptile * 64) * KC;
    const __bf16* Apl = xl + ((size_t)cb * HW + ptile * 64) * KC;
    const __bf16* Bph = wh + ((size_t)cb * NPAD2 + ntile * 128) * KC;
    const __bf16* Bpl = wl + ((size_t)cb * NPAD2 + ntile * 128) * KC;

    f32x4 acc[4][2];
#pragma unroll
    for (int i = 0; i < 4; ++i)
#pragma unroll
        for (int j = 0; j < 2; ++j) acc[i][j] = (f32x4){0.f, 0.f, 0.f, 0.f};

    int lr = tid >> 2, lk = (tid & 3) * 8;
    for (int k0 = 0; k0 < KC; k0 += 32) {
        *(bf16x8*)&Ah[lr * 40 + lk] = *(const bf16x8*)(Aph + (size_t)lr * KC + k0 + lk);
        *(bf16x8*)&Al[lr * 40 + lk] = *(const bf16x8*)(Apl + (size_t)lr * KC + k0 + lk);
#pragma unroll
        for (int i = 0; i < 2; ++i) {
            int r = tid + i * 256;
            int rr = r >> 2, rk = (r & 3) * 8;
            *(bf16x8*)&Bh[rr * 40 + rk] = *(const bf16x8*)(Bph + (size_t)rr * KC + k0 + rk);
            *(bf16x8*)&Bl[rr * 40 + rk] = *(const bf16x8*)(Bpl + (size_t)rr * KC + k0 + rk);
        }
        __syncthreads();
        bf16x8 ah[4], al[4], bh[2], bl[2];
#pragma unroll
        for (int m = 0; m < 4; ++m) {
            ah[m] = *(const bf16x8*)&Ah[(m * 16 + row16) * 40 + quad * 8];
            al[m] = *(const bf16x8*)&Al[(m * 16 + row16) * 40 + quad * 8];
        }
#pragma unroll
        for (int nb = 0; nb < 2; ++nb) {
            bh[nb] = *(const bf16x8*)&Bh[(wave * 32 + nb * 16 + row16) * 40 + quad * 8];
            bl[nb] = *(const bf16x8*)&Bl[(wave * 32 + nb * 16 + row16) * 40 + quad * 8];
        }
#pragma unroll
        for (int m = 0; m < 4; ++m)
#pragma unroll
            for (int nb = 0; nb < 2; ++nb) {
                acc[m][nb] = __builtin_amdgcn_mfma_f32_16x16x32_bf16(ah[m], bh[nb], acc[m][nb], 0, 0, 0);
                acc[m][nb] = __builtin_amdgcn_mfma_f32_16x16x32_bf16(ah[m], bl[nb], acc[m][nb], 0, 0, 0);
                acc[m][nb] = __builtin_amdgcn_mfma_f32_16x16x32_bf16(al[m], bh[nb], acc[m][nb], 0, 0, 0);
            }
        __syncthreads();
    }

    int nn[2];
    float sv[2];
    bool valid[2];
#pragma unroll
    for (int nb = 0; nb < 2; ++nb) {
        nn[nb] = ntile * 128 + wave * 32 + nb * 16 + row16;
        valid[nb] = nn[nb] < NTOT;
        sv[nb] = valid[nb] ? sinv[(size_t)(b0 + cb) * NTOT + nn[nb]] : 0.f;
    }
    float sm[4][4] = {};
#pragma unroll
    for (int m = 0; m < 4; ++m)
#pragma unroll
        for (int nb = 0; nb < 2; ++nb) {
            size_t rb = ((size_t)cb * HW + ptile * 64 + m * 16) * NPAD2 + nn[nb];
#pragma unroll
            for (int r = 0; r < 4; ++r) {
                float mub = sMub[m * 16 + quad * 4 + r];
                float e = valid[nb] ? __expf(acc[m][nb][r] * sv[nb] - mub) : 0.f;
                tbuf[rb + (size_t)(quad * 4 + r) * NPAD2] = (__bf16)e;
                sm[m][r] += e;
            }
        }
#pragma unroll
    for (int msk = 1; msk < 16; msk <<= 1)
#pragma unroll
        for (int m = 0; m < 4; ++m)
#pragma unroll
            for (int r = 0; r < 4; ++r) sm[m][r] += __shfl_xor(sm[m][r], msk, 64);
    if (row16 == 0)
#pragma unroll
        for (int m = 0; m < 4; ++m)
#pragma unroll
            for (int r = 0; r < 4; ++r) redS[wave][m * 16 + quad * 4 + r] = sm[m][r];
    __syncthreads();
    if (wave == 0 && row16 == 0) {
#pragma unroll
        for (int m = 0; m < 4; ++m)
#pragma unroll
            for (int r = 0; r < 4; ++r) {
                int p = m * 16 + quad * 4 + r;
                float S = redS[0][p] + redS[1][p] + redS[2][p] + redS[3][p];
                partS[((size_t)cb * HW + ptile * 64 + p) * NT26 + ntile] = S;
            }
    }
}

// ---------------- row sum reduce ----------------
__global__ void k_rowsum(const float* __restrict__ partS, float* __restrict__ fin) {
    int row = blockIdx.x * 256 + threadIdx.x;
    float s = 0.f;
#pragma unroll
    for (int nt = 0; nt < NT26; ++nt) s += partS[(size_t)row * NT26 + nt];
    fin[row] = 1.0f / fmaxf(s, 1e-38f);
}

// ---------------- fold GEMM (MFMA bf16, K-step 64, reg prefetch) ----------------
#define FSTR 72   // LDS row stride in bf16 (144 B, 16B-aligned)
__global__ void k_fold_mfma(const __bf16* __restrict__ Vb, const __bf16* __restrict__ tbuf,
                            const float* __restrict__ fin, float* __restrict__ outacc) {
    int ptile = blockIdx.x;   // 8 tiles of 128 p
    int mtile = blockIdx.y;   // 9 tiles of 64 m
    int cb    = blockIdx.z;
    int tid  = threadIdx.x;
    int lane = tid & 63, wave = tid >> 6;
    int row16 = lane & 15, quad = lane >> 4;

    __shared__ __bf16 Als[64 * FSTR];
    __shared__ __bf16 Bls[128 * FSTR];

    const __bf16* Vp = Vb   + (size_t)cb * 576 * NPAD2 + (size_t)mtile * 64 * NPAD2;
    const __bf16* Pp = tbuf + (size_t)cb * HW  * NPAD2 + (size_t)ptile * 128 * NPAD2;

    f32x4 acc[4][2];
#pragma unroll
    for (int i = 0; i < 4; ++i)
#pragma unroll
        for (int j = 0; j < 2; ++j) acc[i][j] = (f32x4){0.f, 0.f, 0.f, 0.f};

    int sr = tid >> 3, sk = (tid & 7) * 8;   // staging: 32 rows/pass, 64 k
    bf16x8 pa[2], pb[4];
#pragma unroll
    for (int i = 0; i < 2; ++i)
        pa[i] = *(const bf16x8*)(Vp + (size_t)(i * 32 + sr) * NPAD2 + sk);
#pragma unroll
    for (int i = 0; i < 4; ++i)
        pb[i] = *(const bf16x8*)(Pp + (size_t)(i * 32 + sr) * NPAD2 + sk);

    for (int k0 = 0; k0 < NPAD2; k0 += 64) {
        __syncthreads();
#pragma unroll
        for (int i = 0; i < 2; ++i)
            *(bf16x8*)&Als[(i * 32 + sr) * FSTR + sk] = pa[i];
#pragma unroll
        for (int i = 0; i < 4; ++i)
            *(bf16x8*)&Bls[(i * 32 + sr) * FSTR + sk] = pb[i];
        if (k0 + 64 < NPAD2) {
#pragma unroll
            for (int i = 0; i < 2; ++i)
                pa[i] = *(const bf16x8*)(Vp + (size_t)(i * 32 + sr) * NPAD2 + k0 + 64 + sk);
#pragma unroll
            for (int i = 0; i < 4; ++i)
                pb[i] = *(const bf16x8*)(Pp + (size_t)(i * 32 + sr) * NPAD2 + k0 + 64 + sk);
        }
        __syncthreads();
#pragma unroll
        for (int kh = 0; kh < 2; ++kh) {
            bf16x8 af[4], bf[2];
#pragma unroll
            for (int mb = 0; mb < 4; ++mb)
                af[mb] = *(const bf16x8*)&Als[(mb * 16 + row16) * FSTR + kh * 32 + quad * 8];
#pragma unroll
            for (int pbi = 0; pbi < 2; ++pbi)
                bf[pbi] = *(const bf16x8*)&Bls[(wave * 32 + pbi * 16 + row16) * FSTR + kh * 32 + quad * 8];
#pragma unroll
            for (int mb = 0; mb < 4; ++mb)
#pragma unroll
                for (int pbi = 0; pbi < 2; ++pbi)
                    acc[mb][pbi] = __builtin_amdgcn_mfma_f32_16x16x32_bf16(af[mb], bf[pbi], acc[mb][pbi], 0, 0, 0);
        }
    }
    float fsc[2];
#pragma unroll
    for (int pbi = 0; pbi < 2; ++pbi)
        fsc[pbi] = fin[(size_t)cb * HW + ptile * 128 + wave * 32 + pbi * 16 + row16];
#pragma unroll
    for (int mb = 0; mb < 4; ++mb)
#pragma unroll
        for (int pbi = 0; pbi < 2; ++pbi) {
#pragma unroll
            for (int r = 0; r < 4; ++r) {
                int mg = mtile * 64 + mb * 16 + quad * 4 + r;
                int pg = ptile * 128 + wave * 32 + pbi * 16 + row16;
                outacc[((size_t)cb * 576 + mg) * HW + pg] = acc[mb][pbi][r] * fsc[pbi];
            }
        }
}

// ---------------- epilogue ----------------
__global__ void k_epilogue(const float* __restrict__ x, const float* __restrict__ outacc,
                           float* __restrict__ out, int b0) {
    int t = blockIdx.x * blockDim.x + threadIdx.x;
    int cb = t >> 16;
    int c = (t >> 10) & 63;
    int p = t & 1023;
    int b = b0 + cb;
    int y = p >> 5, xx = p & 31;
    float acc = 0.f;
#pragma unroll
    for (int ky = 0; ky < 3; ++ky)
#pragma unroll
        for (int kx = 0; kx < 3; ++kx) {
            int py = y + 1 - ky, px = xx + 1 - kx;
            if (py >= 0 && py < HH && px >= 0 && px < WW)
                acc += outacc[((size_t)cb * 576 + c * 9 + ky * 3 + kx) * HW + py * WW + px];
        }
    size_t o = ((size_t)b * CC + c) * HW + p;
    out[o] = x[o] + 0.25f * acc;
}

extern "C" void kernel_launch(void* const* d_in, const int* in_sizes, int n_in,
                              void* d_out, int out_size, void* d_ws, size_t ws_size,
                              hipStream_t stream) {
    const float* x       = (const float*)d_in[0];
    const float* w_base  = (const float*)d_in[1];
    const float* b_base  = (const float*)d_in[2];
    const float* a_base  = (const float*)d_in[3];
    const float* w_match = (const float*)d_in[4];
    const float* b_match = (const float*)d_in[5];
    const float* a_match = (const float*)d_in[6];
    const float* w_asm   = (const float*)d_in[7];
    const float* b_asm   = (const float*)d_in[8];
    const float* a_asm   = (const float*)d_in[9];
    float* out = (float*)d_out;

    const size_t fixed = ((size_t)BB * C2 * HW * 4) * 2 + ((size_t)BB * CC * HW * 2) +
                         ((size_t)BB * HW * 4) * 3 + ((size_t)BB * NTOT * 4) +
                         ((size_t)9 * NTOT * 4) + 65536;
    const size_t perCB = ((size_t)HW * KC * 2 * 2) + ((size_t)NPAD2 * KC * 2 * 2) +
                         ((size_t)HW * NPAD2 * 2) + ((size_t)HW * NT26 * 4) +
                         ((size_t)HW * 4) + ((size_t)576 * NPAD2 * 2) +
                         ((size_t)576 * HW * 4) + 65536;
    int CB = 32;
    while (CB > 1 && fixed + perCB * CB > ws_size) CB >>= 1;

    char* ws = (char*)d_ws;
    size_t off = 0;
    auto alloc_b = [&](size_t bytes) {
        void* p = (void*)(ws + off);
        off += bytes;
        off = (off + 255) & ~(size_t)255;
        return p;
    };
    float*  mb      = (float*)alloc_b((size_t)BB * C2 * HW * 4);
    float*  rm_full = (float*)alloc_b((size_t)BB * C2 * HW * 4);
    __bf16* base_f  = (__bf16*)alloc_b((size_t)BB * CC * HW * 2);
    float*  mbss    = (float*)alloc_b((size_t)BB * HW * 4);
    float*  rmss    = (float*)alloc_b((size_t)BB * HW * 4);
    float*  qub     = (float*)alloc_b((size_t)BB * HW * 4);
    float*  sinv    = (float*)alloc_b((size_t)BB * NTOT * 4);
    int*    nbr_pos = (int*)alloc_b((size_t)9 * NTOT * 4);
    __bf16* xpat_h  = (__bf16*)alloc_b((size_t)CB * HW * KC * 2);
    __bf16* xpat_l  = (__bf16*)alloc_b((size_t)CB * HW * KC * 2);
    __bf16* wib_h   = (__bf16*)alloc_b((size_t)CB * NPAD2 * KC * 2);
    __bf16* wib_l   = (__bf16*)alloc_b((size_t)CB * NPAD2 * KC * 2);
    __bf16* tbuf    = (__bf16*)alloc_b((size_t)CB * HW * NPAD2 * 2);
    float*  partS   = (float*)alloc_b((size_t)CB * HW * NT26 * 4);
    float*  fin     = (float*)alloc_b((size_t)CB * HW * 4);
    __bf16* Vb      = (__bf16*)alloc_b((size_t)CB * 576 * NPAD2 * 2);
    float*  outacc  = (float*)alloc_b((size_t)CB * 576 * HW * 4);
    if (off > ws_size) return;

    k_feats<<<BB * HW / 64, 256, 0, stream>>>(
        x, w_base, b_base, a_base, w_match, b_match, a_match, w_asm, b_asm, a_asm,
        mb, rm_full, base_f, mbss, rmss);
    k_nbr<<<(NTOT + 255) / 256, 256, 0, stream>>>(nbr_pos);
    k_qnorm<<<BB * HW / 256, 256, 0, stream>>>(mbss, qub);
    k_norms<<<(BB * NTOT + 255) / 256, 256, 0, stream>>>(rmss, nbr_pos, sinv);

    for (int b0 = 0; b0 < BB; b0 += CB) {
        k_xpat<<<dim3(HW * 36 / 256, CB), 256, 0, stream>>>(mb, xpat_h, xpat_l, b0);
        k_wib<<<dim3(NPAD2 * 36 / 256, CB), 256, 0, stream>>>(rm_full, nbr_pos, wib_h, wib_l, b0);
        k_corr_mfma<<<dim3(16, NT26, CB), 256, 0, stream>>>(
            xpat_h, xpat_l, wib_h, wib_l, sinv, qub, tbuf, partS, b0);
        k_rowsum<<<CB * HW / 256, 256, 0, stream>>>(partS, fin);
        k_vgather<<<dim3(576 * (NPAD2 / 8) / 256, CB), 256, 0, stream>>>(base_f, nbr_pos, Vb, b0);
        k_fold_mfma<<<dim3(8, 9, CB), 256, 0, stream>>>(Vb, tbuf, fin, outacc);
        k_epilogue<<<CB * CC * HW / 256, 256, 0, stream>>>(x, outacc, out, b0);
    }
}

// Round 10
// 768.795 us; speedup vs baseline: 1.8700x; 1.2256x over previous
//
#include <hip/hip_runtime.h>
#include <hip/hip_bf16.h>
#include <math.h>

#define BB 32
#define CC 64
#define C2 32
#define HH 32
#define WW 32
#define HW 1024
#define NTOT 3278
#define NPAD2 3328   // padded N (multiple of 128) for MFMA corr + fold
#define NT26 26      // NPAD2 / 128
#define KC 288       // correlation K = C2*9

typedef __bf16 bf16x8 __attribute__((ext_vector_type(8)));
typedef float  f32x4  __attribute__((ext_vector_type(4)));

__device__ __constant__ int SC_SIZE[5] = {32, 28, 25, 22, 19};
__device__ __constant__ int SC_OFF[6]  = {0, 1024, 1808, 2433, 2917, 3278};

// ---------------- fused feature kernel: LDS-staged, x read once ----------------
// og0: mbt hi/lo transposed [p][32c] + mbss; og1: rmt hi/lo + rmss; og2/3: basef bf16 [c][p]
#define XS_STR 65
#define WS_STR 132
__global__ void __launch_bounds__(256, 1) k_feats(
        const float* __restrict__ x,
        const float* __restrict__ wb, const float* __restrict__ bb, const float* __restrict__ ab,
        const float* __restrict__ wm, const float* __restrict__ bm, const float* __restrict__ am,
        const float* __restrict__ wa, const float* __restrict__ ba, const float* __restrict__ aa,
        __bf16* __restrict__ mbt_h, __bf16* __restrict__ mbt_l,
        __bf16* __restrict__ rmt_h, __bf16* __restrict__ rmt_l,
        __bf16* __restrict__ basef,
        float* __restrict__ mbss, float* __restrict__ rmss) {
    __shared__ float Xs[64 * XS_STR];     // [c][p]
    __shared__ float Wls[64 * WS_STR];    // [c][o]
    __shared__ float bsh[128];
    __shared__ float ash3[3];
    int tid = threadIdx.x;
    int g0 = blockIdx.x * 64;
    int b = g0 >> 10, p0 = g0 & 1023;

    const float* xb = x + (size_t)b * CC * HW + p0;
    for (int i = tid; i < 64 * 64; i += 256) {
        int c = i >> 6, p = i & 63;
        Xs[c * XS_STR + p] = xb[(size_t)c * HW + p];
    }
    for (int i = tid; i < 128 * 64; i += 256) {
        int o = i >> 6, c = i & 63;
        float w = (o < 32) ? wb[o * CC + c] : (o < 64) ? wm[(o - 32) * CC + c] : wa[(o - 64) * CC + c];
        Wls[c * WS_STR + o] = w;
    }
    if (tid < 128) bsh[tid] = (tid < 32) ? bb[tid] : (tid < 64) ? bm[tid - 32] : ba[tid - 64];
    if (tid == 128) ash3[0] = ab[0];
    if (tid == 129) ash3[1] = am[0];
    if (tid == 130) ash3[2] = aa[0];
    __syncthreads();

    int p = tid & 63, og = tid >> 6;
    int o0 = og * 32;
    float acc[32];
#pragma unroll
    for (int oi = 0; oi < 32; ++oi) acc[oi] = bsh[o0 + oi];
    for (int c = 0; c < 64; ++c) {
        float xv = Xs[c * XS_STR + p];
        const float* wr = &Wls[c * WS_STR + o0];
#pragma unroll
        for (int oi = 0; oi < 32; ++oi) acc[oi] += wr[oi] * xv;
    }
    int pp = p0 + p;
    if (og < 2) {
        float alpha = ash3[og], ss = 0.f;
        bf16x8 hi[4], lo[4];
#pragma unroll
        for (int oi = 0; oi < 32; ++oi) {
            float v = acc[oi] >= 0.f ? acc[oi] : alpha * acc[oi];
            ss += v * v;
            __bf16 h = (__bf16)v;
            hi[oi >> 3][oi & 7] = h;
            lo[oi >> 3][oi & 7] = (__bf16)(v - (float)h);
        }
        __bf16* dh = (og == 0 ? mbt_h : rmt_h) + ((size_t)b * HW + pp) * 32;
        __bf16* dl = (og == 0 ? mbt_l : rmt_l) + ((size_t)b * HW + pp) * 32;
#pragma unroll
        for (int q = 0; q < 4; ++q) {
            *(bf16x8*)&dh[q * 8] = hi[q];
            *(bf16x8*)&dl[q * 8] = lo[q];
        }
        if (og == 0) mbss[(size_t)b * HW + pp] = ss;
        else         rmss[(size_t)b * HW + pp] = ss;
    } else {
        float alpha = ash3[2];
        int ob = o0 - 64;
#pragma unroll
        for (int oi = 0; oi < 32; ++oi) {
            float v = acc[oi] >= 0.f ? acc[oi] : alpha * acc[oi];
            basef[((size_t)b * CC + ob + oi) * HW + pp] = (__bf16)v;
        }
    }
}

// ---------------- neighbor table ----------------
__global__ void k_nbr(int* __restrict__ nbr_pos) {
    int n = blockIdx.x * blockDim.x + threadIdx.x;
    if (n >= NTOT) return;
    int s = 0;
    while (s < 4 && n >= SC_OFF[s + 1]) ++s;
    int q = n - SC_OFF[s];
    int hs = SC_SIZE[s];
    int ny = q / hs, nx = q % hs;
    for (int dy = 0; dy < 3; ++dy)
        for (int dx = 0; dx < 3; ++dx) {
            int yy = ny + dy - 1, xx = nx + dx - 1;
            int pos = -1;
            if (yy >= 0 && yy < hs && xx >= 0 && xx < hs)
                pos = ((yy * HH) / hs) * WW + (xx * WW) / hs;
            nbr_pos[(dy * 3 + dx) * NTOT + n] = pos;
        }
}

// ---------------- per-(b,p) logit upper bound ----------------
__global__ void k_qnorm(const float* __restrict__ mbss, float* __restrict__ qub) {
    int t = blockIdx.x * blockDim.x + threadIdx.x;
    int b = t >> 10, p = t & 1023;
    int y = p >> 5, x = p & 31;
    float s = 0.f;
#pragma unroll
    for (int dy = 0; dy < 3; ++dy)
#pragma unroll
        for (int dx = 0; dx < 3; ++dx) {
            int yy = y + dy - 1, xx = x + dx - 1;
            if (yy >= 0 && yy < HH && xx >= 0 && xx < WW)
                s += mbss[(size_t)b * HW + yy * WW + xx];
        }
    qub[t] = 10.0f * sqrtf(s);
}

// ---------------- per-(b,n) filter norms ----------------
__global__ void k_norms(const float* __restrict__ rmss, const int* __restrict__ nbr_pos,
                        float* __restrict__ sinv) {
    int t = blockIdx.x * blockDim.x + threadIdx.x;
    if (t >= BB * NTOT) return;
    int b = t / NTOT, n = t % NTOT;
    float sum = 0.f;
#pragma unroll
    for (int kk = 0; kk < 9; ++kk) {
        int pos = nbr_pos[kk * NTOT + n];
        if (pos >= 0) sum += rmss[(size_t)b * HW + pos];
    }
    sinv[t] = 10.0f / fmaxf(sqrtf(sum), 1e-4f);
}

// ---------------- V gather (vectorized): thread -> 8 consecutive n ----------------
__global__ void k_vgather(const __bf16* __restrict__ basef, const int* __restrict__ nbr_pos,
                          __bf16* __restrict__ Vb, int b0) {
    int t = blockIdx.x * 256 + threadIdx.x;   // over 576*(NPAD2/8)
    int cb = blockIdx.y;
    int m = t / (NPAD2 / 8), nq = t % (NPAD2 / 8);
    int c = m / 9, kk = m - c * 9;
    const __bf16* bfp = basef + ((size_t)(b0 + cb) * CC + c) * HW;
    const int* nb = &nbr_pos[kk * NTOT];
    int n0 = nq * 8;
    bf16x8 v8;
#pragma unroll
    for (int u = 0; u < 8; ++u) {
        int n = n0 + u;
        __bf16 v = (__bf16)0.f;
        if (n < NTOT) {
            int pos = nb[n];
            if (pos >= 0) v = bfp[pos];
        }
        v8[u] = v;
    }
    *(bf16x8*)&Vb[((size_t)cb * 576 + m) * NPAD2 + n0] = v8;
}

// ---------------- correlation GEMM: transposed-operand fused gather + split-bf16 MFMA ----------------
// K reordered as k' = kk*32 + c2 (both operands, dot order only). 9 K-steps of 32.
__global__ void k_corr_mfma(const __bf16* __restrict__ mbt_h, const __bf16* __restrict__ mbt_l,
                            const __bf16* __restrict__ rmt_h, const __bf16* __restrict__ rmt_l,
                            const int* __restrict__ nbr_pos,
                            const float* __restrict__ sinv, const float* __restrict__ qub,
                            __bf16* __restrict__ tbuf, float* __restrict__ partS, int b0) {
    int ptile = blockIdx.x;   // 16 tiles of 64 p
    int ntile = blockIdx.y;   // 26 tiles of 128 n
    int cb    = blockIdx.z;
    int tid  = threadIdx.x;
    int lane = tid & 63, wave = tid >> 6;
    int row16 = lane & 15, quad = lane >> 4;
    int p0 = ptile * 64, n0 = ntile * 128;

    __shared__ __bf16 Ah[64 * 40], Al[64 * 40];
    __shared__ __bf16 Bh[128 * 40], Bl[128 * 40];
    __shared__ int   nbrs[9][128];
    __shared__ float sMub[64];
    __shared__ float redS[4][64];

    if (tid < 64) sMub[tid] = qub[(size_t)(b0 + cb) * HW + p0 + tid];
    for (int i = tid; i < 9 * 128; i += 256) {
        int kk = i >> 7, j = i & 127;
        int n = n0 + j;
        nbrs[kk][j] = (n < NTOT) ? nbr_pos[kk * NTOT + n] : -1;
    }

    const __bf16* mh = mbt_h + (size_t)(b0 + cb) * HW * 32;
    const __bf16* ml = mbt_l + (size_t)(b0 + cb) * HW * 32;
    const __bf16* rh = rmt_h + (size_t)(b0 + cb) * HW * 32;
    const __bf16* rl = rmt_l + (size_t)(b0 + cb) * HW * 32;

    f32x4 acc[4][2];
#pragma unroll
    for (int i = 0; i < 4; ++i)
#pragma unroll
        for (int j = 0; j < 2; ++j) acc[i][j] = (f32x4){0.f, 0.f, 0.f, 0.f};

    bf16x8 zero8;
#pragma unroll
    for (int u = 0; u < 8; ++u) zero8[u] = (__bf16)0.f;

    int ap = tid >> 2, ac = (tid & 3) * 8;     // A task: (p-local, c-oct)
    int pg = p0 + ap, ay = pg >> 5, ax = pg & 31;

    __syncthreads();   // nbrs ready

    for (int kk = 0; kk < 9; ++kk) {
        // ---- A: one 16B load per (p, c-oct) from transposed mbt ----
        {
            int py = ay + kk / 3 - 1, px = ax + (kk % 3) - 1;
            bool av = (py >= 0 && py < HH && px >= 0 && px < WW);
            size_t apos = (size_t)(py * WW + px) * 32 + ac;
            *(bf16x8*)&Ah[ap * 40 + ac] = av ? *(const bf16x8*)(mh + apos) : zero8;
            *(bf16x8*)&Al[ap * 40 + ac] = av ? *(const bf16x8*)(ml + apos) : zero8;
        }
        // ---- B: one 16B load per (n, c-oct) from transposed rmt via nbrs ----
#pragma unroll
        for (int it = 0; it < 2; ++it) {
            int tt = tid + it * 256;
            int bn = tt >> 2, bc = (tt & 3) * 8;
            int pos = nbrs[kk][bn];
            if (pos >= 0) {
                size_t bposo = (size_t)pos * 32 + bc;
                *(bf16x8*)&Bh[bn * 40 + bc] = *(const bf16x8*)(rh + bposo);
                *(bf16x8*)&Bl[bn * 40 + bc] = *(const bf16x8*)(rl + bposo);
            } else {
                *(bf16x8*)&Bh[bn * 40 + bc] = zero8;
                *(bf16x8*)&Bl[bn * 40 + bc] = zero8;
            }
        }
        __syncthreads();
        bf16x8 ah[4], al[4], bh[2], bl[2];
#pragma unroll
        for (int m = 0; m < 4; ++m) {
            ah[m] = *(const bf16x8*)&Ah[(m * 16 + row16) * 40 + quad * 8];
            al[m] = *(const bf16x8*)&Al[(m * 16 + row16) * 40 + quad * 8];
        }
#pragma unroll
        for (int nb = 0; nb < 2; ++nb) {
            bh[nb] = *(const bf16x8*)&Bh[(wave * 32 + nb * 16 + row16) * 40 + quad * 8];
            bl[nb] = *(const bf16x8*)&Bl[(wave * 32 + nb * 16 + row16) * 40 + quad * 8];
        }
#pragma unroll
        for (int m = 0; m < 4; ++m)
#pragma unroll
            for (int nb = 0; nb < 2; ++nb) {
                acc[m][nb] = __builtin_amdgcn_mfma_f32_16x16x32_bf16(ah[m], bh[nb], acc[m][nb], 0, 0, 0);
                acc[m][nb] = __builtin_amdgcn_mfma_f32_16x16x32_bf16(ah[m], bl[nb], acc[m][nb], 0, 0, 0);
                acc[m][nb] = __builtin_amdgcn_mfma_f32_16x16x32_bf16(al[m], bh[nb], acc[m][nb], 0, 0, 0);
            }
        __syncthreads();
    }

    // ---- epilogue: v = acc*sinv[n]; t = exp(v - Mub[p]); row-partial sums ----
    int nn[2];
    float sv[2];
    bool valid[2];
#pragma unroll
    for (int nb = 0; nb < 2; ++nb) {
        nn[nb] = n0 + wave * 32 + nb * 16 + row16;
        valid[nb] = nn[nb] < NTOT;
        sv[nb] = valid[nb] ? sinv[(size_t)(b0 + cb) * NTOT + nn[nb]] : 0.f;
    }
    float sm[4][4] = {};
#pragma unroll
    for (int m = 0; m < 4; ++m)
#pragma unroll
        for (int nb = 0; nb < 2; ++nb) {
            size_t rb = ((size_t)cb * HW + p0 + m * 16) * NPAD2 + nn[nb];
#pragma unroll
            for (int r = 0; r < 4; ++r) {
                float mub = sMub[m * 16 + quad * 4 + r];
                float e = valid[nb] ? __expf(acc[m][nb][r] * sv[nb] - mub) : 0.f;
                tbuf[rb + (size_t)(quad * 4 + r) * NPAD2] = (__bf16)e;
                sm[m][r] += e;
            }
        }
#pragma unroll
    for (int msk = 1; msk < 16; msk <<= 1)
#pragma unroll
        for (int m = 0; m < 4; ++m)
#pragma unroll
            for (int r = 0; r < 4; ++r) sm[m][r] += __shfl_xor(sm[m][r], msk, 64);
    if (row16 == 0)
#pragma unroll
        for (int m = 0; m < 4; ++m)
#pragma unroll
            for (int r = 0; r < 4; ++r) redS[wave][m * 16 + quad * 4 + r] = sm[m][r];
    __syncthreads();
    if (wave == 0 && row16 == 0) {
#pragma unroll
        for (int m = 0; m < 4; ++m)
#pragma unroll
            for (int r = 0; r < 4; ++r) {
                int p = m * 16 + quad * 4 + r;
                float S = redS[0][p] + redS[1][p] + redS[2][p] + redS[3][p];
                partS[((size_t)cb * HW + p0 + p) * NT26 + ntile] = S;
            }
    }
}

// ---------------- row sum reduce ----------------
__global__ void k_rowsum(const float* __restrict__ partS, float* __restrict__ fin) {
    int row = blockIdx.x * 256 + threadIdx.x;
    float s = 0.f;
#pragma unroll
    for (int nt = 0; nt < NT26; ++nt) s += partS[(size_t)row * NT26 + nt];
    fin[row] = 1.0f / fmaxf(s, 1e-38f);
}

// ---------------- fold GEMM (MFMA bf16, K-step 64, reg prefetch) ----------------
#define FSTR 72   // LDS row stride in bf16 (144 B, 16B-aligned)
__global__ void k_fold_mfma(const __bf16* __restrict__ Vb, const __bf16* __restrict__ tbuf,
                            const float* __restrict__ fin, float* __restrict__ outacc) {
    int ptile = blockIdx.x;   // 8 tiles of 128 p
    int mtile = blockIdx.y;   // 9 tiles of 64 m
    int cb    = blockIdx.z;
    int tid  = threadIdx.x;
    int lane = tid & 63, wave = tid >> 6;
    int row16 = lane & 15, quad = lane >> 4;

    __shared__ __bf16 Als[64 * FSTR];
    __shared__ __bf16 Bls[128 * FSTR];

    const __bf16* Vp = Vb   + (size_t)cb * 576 * NPAD2 + (size_t)mtile * 64 * NPAD2;
    const __bf16* Pp = tbuf + (size_t)cb * HW  * NPAD2 + (size_t)ptile * 128 * NPAD2;

    f32x4 acc[4][2];
#pragma unroll
    for (int i = 0; i < 4; ++i)
#pragma unroll
        for (int j = 0; j < 2; ++j) acc[i][j] = (f32x4){0.f, 0.f, 0.f, 0.f};

    int sr = tid >> 3, sk = (tid & 7) * 8;   // staging: 32 rows/pass, 64 k
    bf16x8 pa[2], pb[4];
#pragma unroll
    for (int i = 0; i < 2; ++i)
        pa[i] = *(const bf16x8*)(Vp + (size_t)(i * 32 + sr) * NPAD2 + sk);
#pragma unroll
    for (int i = 0; i < 4; ++i)
        pb[i] = *(const bf16x8*)(Pp + (size_t)(i * 32 + sr) * NPAD2 + sk);

    for (int k0 = 0; k0 < NPAD2; k0 += 64) {
        __syncthreads();
#pragma unroll
        for (int i = 0; i < 2; ++i)
            *(bf16x8*)&Als[(i * 32 + sr) * FSTR + sk] = pa[i];
#pragma unroll
        for (int i = 0; i < 4; ++i)
            *(bf16x8*)&Bls[(i * 32 + sr) * FSTR + sk] = pb[i];
        if (k0 + 64 < NPAD2) {
#pragma unroll
            for (int i = 0; i < 2; ++i)
                pa[i] = *(const bf16x8*)(Vp + (size_t)(i * 32 + sr) * NPAD2 + k0 + 64 + sk);
#pragma unroll
            for (int i = 0; i < 4; ++i)
                pb[i] = *(const bf16x8*)(Pp + (size_t)(i * 32 + sr) * NPAD2 + k0 + 64 + sk);
        }
        __syncthreads();
#pragma unroll
        for (int kh = 0; kh < 2; ++kh) {
            bf16x8 af[4], bf[2];
#pragma unroll
            for (int mb = 0; mb < 4; ++mb)
                af[mb] = *(const bf16x8*)&Als[(mb * 16 + row16) * FSTR + kh * 32 + quad * 8];
#pragma unroll
            for (int pbi = 0; pbi < 2; ++pbi)
                bf[pbi] = *(const bf16x8*)&Bls[(wave * 32 + pbi * 16 + row16) * FSTR + kh * 32 + quad * 8];
#pragma unroll
            for (int mb = 0; mb < 4; ++mb)
#pragma unroll
                for (int pbi = 0; pbi < 2; ++pbi)
                    acc[mb][pbi] = __builtin_amdgcn_mfma_f32_16x16x32_bf16(af[mb], bf[pbi], acc[mb][pbi], 0, 0, 0);
        }
    }
    float fsc[2];
#pragma unroll
    for (int pbi = 0; pbi < 2; ++pbi)
        fsc[pbi] = fin[(size_t)cb * HW + ptile * 128 + wave * 32 + pbi * 16 + row16];
#pragma unroll
    for (int mb = 0; mb < 4; ++mb)
#pragma unroll
        for (int pbi = 0; pbi < 2; ++pbi) {
#pragma unroll
            for (int r = 0; r < 4; ++r) {
                int mg = mtile * 64 + mb * 16 + quad * 4 + r;
                int pg = ptile * 128 + wave * 32 + pbi * 16 + row16;
                outacc[((size_t)cb * 576 + mg) * HW + pg] = acc[mb][pbi][r] * fsc[pbi];
            }
        }
}

// ---------------- epilogue ----------------
__global__ void k_epilogue(const float* __restrict__ x, const float* __restrict__ outacc,
                           float* __restrict__ out, int b0) {
    int t = blockIdx.x * blockDim.x + threadIdx.x;
    int cb = t >> 16;
    int c = (t >> 10) & 63;
    int p = t & 1023;
    int b = b0 + cb;
    int y = p >> 5, xx = p & 31;
    float acc = 0.f;
#pragma unroll
    for (int ky = 0; ky < 3; ++ky)
#pragma unroll
        for (int kx = 0; kx < 3; ++kx) {
            int py = y + 1 - ky, px = xx + 1 - kx;
            if (py >= 0 && py < HH && px >= 0 && px < WW)
                acc += outacc[((size_t)cb * 576 + c * 9 + ky * 3 + kx) * HW + py * WW + px];
        }
    size_t o = ((size_t)b * CC + c) * HW + p;
    out[o] = x[o] + 0.25f * acc;
}

extern "C" void kernel_launch(void* const* d_in, const int* in_sizes, int n_in,
                              void* d_out, int out_size, void* d_ws, size_t ws_size,
                              hipStream_t stream) {
    const float* x       = (const float*)d_in[0];
    const float* w_base  = (const float*)d_in[1];
    const float* b_base  = (const float*)d_in[2];
    const float* a_base  = (const float*)d_in[3];
    const float* w_match = (const float*)d_in[4];
    const float* b_match = (const float*)d_in[5];
    const float* a_match = (const float*)d_in[6];
    const float* w_asm   = (const float*)d_in[7];
    const float* b_asm   = (const float*)d_in[8];
    const float* a_asm   = (const float*)d_in[9];
    float* out = (float*)d_out;

    const size_t fixed = ((size_t)BB * HW * 32 * 2) * 4 + ((size_t)BB * CC * HW * 2) +
                         ((size_t)BB * HW * 4) * 3 + ((size_t)BB * NTOT * 4) +
                         ((size_t)9 * NTOT * 4) + 65536;
    const size_t perCB = ((size_t)HW * NPAD2 * 2) + ((size_t)HW * NT26 * 4) +
                         ((size_t)HW * 4) + ((size_t)576 * NPAD2 * 2) +
                         ((size_t)576 * HW * 4) + 65536;
    int CB = 32;
    while (CB > 1 && fixed + perCB * CB > ws_size) CB >>= 1;

    char* ws = (char*)d_ws;
    size_t off = 0;
    auto alloc_b = [&](size_t bytes) {
        void* p = (void*)(ws + off);
        off += bytes;
        off = (off + 255) & ~(size_t)255;
        return p;
    };
    __bf16* mbt_h   = (__bf16*)alloc_b((size_t)BB * HW * 32 * 2);
    __bf16* mbt_l   = (__bf16*)alloc_b((size_t)BB * HW * 32 * 2);
    __bf16* rmt_h   = (__bf16*)alloc_b((size_t)BB * HW * 32 * 2);
    __bf16* rmt_l   = (__bf16*)alloc_b((size_t)BB * HW * 32 * 2);
    __bf16* base_f  = (__bf16*)alloc_b((size_t)BB * CC * HW * 2);
    float*  mbss    = (float*)alloc_b((size_t)BB * HW * 4);
    float*  rmss    = (float*)alloc_b((size_t)BB * HW * 4);
    float*  qub     = (float*)alloc_b((size_t)BB * HW * 4);
    float*  sinv    = (float*)alloc_b((size_t)BB * NTOT * 4);
    int*    nbr_pos = (int*)alloc_b((size_t)9 * NTOT * 4);
    __bf16* tbuf    = (__bf16*)alloc_b((size_t)CB * HW * NPAD2 * 2);
    float*  partS   = (float*)alloc_b((size_t)CB * HW * NT26 * 4);
    float*  fin     = (float*)alloc_b((size_t)CB * HW * 4);
    __bf16* Vb      = (__bf16*)alloc_b((size_t)CB * 576 * NPAD2 * 2);
    float*  outacc  = (float*)alloc_b((size_t)CB * 576 * HW * 4);
    if (off > ws_size) return;

    k_feats<<<BB * HW / 64, 256, 0, stream>>>(
        x, w_base, b_base, a_base, w_match, b_match, a_match, w_asm, b_asm, a_asm,
        mbt_h, mbt_l, rmt_h, rmt_l, base_f, mbss, rmss);
    k_nbr<<<(NTOT + 255) / 256, 256, 0, stream>>>(nbr_pos);
    k_qnorm<<<BB * HW / 256, 256, 0, stream>>>(mbss, qub);
    k_norms<<<(BB * NTOT + 255) / 256, 256, 0, stream>>>(rmss, nbr_pos, sinv);

    for (int b0 = 0; b0 < BB; b0 += CB) {
        k_corr_mfma<<<dim3(16, NT26, CB), 256, 0, stream>>>(
            mbt_h, mbt_l, rmt_h, rmt_l, nbr_pos, sinv, qub, tbuf, partS, b0);
        k_rowsum<<<CB * HW / 256, 256, 0, stream>>>(partS, fin);
        k_vgather<<<dim3(576 * (NPAD2 / 8) / 256, CB), 256, 0, stream>>>(base_f, nbr_pos, Vb, b0);
        k_fold_mfma<<<dim3(8, 9, CB), 256, 0, stream>>>(Vb, tbuf, fin, outacc);
        k_epilogue<<<CB * CC * HW / 256, 256, 0, stream>>>(x, outacc, out, b0);
    }
}